// Round 1
// baseline (3356.718 us; speedup 1.0000x reference)
//
#include <hip/hip_runtime.h>

#define NBUS 131072
#define NGEN 32768
#define NEBB 2097152
#define NEGB 65536
#define NEBG 65536

// ---------------- CSR build ----------------
__global__ void k_hist(const int* __restrict__ dst, int* __restrict__ counts, int nE) {
  int stride = gridDim.x * blockDim.x;
  for (int i = blockIdx.x * blockDim.x + threadIdx.x; i < nE; i += stride)
    atomicAdd(&counts[dst[i]], 1);
}

// per-block tile (1024 elems) exclusive scan; bsums[b] = tile total
__global__ void k_scan1(const int* __restrict__ in, int* __restrict__ out,
                        int* __restrict__ bsums, int n) {
  __shared__ int sh[256];
  int t = threadIdx.x;
  int base = blockIdx.x * 1024 + t * 4;
  int v0 = (base + 0 < n) ? in[base + 0] : 0;
  int v1 = (base + 1 < n) ? in[base + 1] : 0;
  int v2 = (base + 2 < n) ? in[base + 2] : 0;
  int v3 = (base + 3 < n) ? in[base + 3] : 0;
  int t0 = v0, t1 = t0 + v1, t2 = t1 + v2, t3 = t2 + v3;
  sh[t] = t3;
  __syncthreads();
  for (int off = 1; off < 256; off <<= 1) {
    int x = (t >= off) ? sh[t - off] : 0;
    __syncthreads();
    sh[t] += x;
    __syncthreads();
  }
  int excl = (t > 0) ? sh[t - 1] : 0;
  if (base + 0 < n) out[base + 0] = excl;
  if (base + 1 < n) out[base + 1] = excl + t0;
  if (base + 2 < n) out[base + 2] = excl + t1;
  if (base + 3 < n) out[base + 3] = excl + t2;
  if (t == 255) bsums[blockIdx.x] = sh[255];
}

// single-block exclusive scan of block sums (nb <= 256)
__global__ void k_scan2(int* __restrict__ bsums, int nb) {
  __shared__ int sh[256];
  int t = threadIdx.x;
  int v = (t < nb) ? bsums[t] : 0;
  sh[t] = v;
  __syncthreads();
  for (int off = 1; off < 256; off <<= 1) {
    int x = (t >= off) ? sh[t - off] : 0;
    __syncthreads();
    sh[t] += x;
    __syncthreads();
  }
  int excl = (t > 0) ? sh[t - 1] : 0;
  if (t < nb) bsums[t] = excl;
}

// add block offsets; copy result into cursor; write offsets[n] = E
__global__ void k_scan3(int* __restrict__ off, int* __restrict__ cur,
                        const int* __restrict__ bsums, int n, int E) {
  int stride = gridDim.x * blockDim.x;
  for (int i = blockIdx.x * blockDim.x + threadIdx.x; i < n; i += stride) {
    int o = off[i] + bsums[i >> 10];
    off[i] = o;
    cur[i] = o;
  }
  if (blockIdx.x == 0 && threadIdx.x == 0) off[n] = E;
}

__global__ void k_fill(const int* __restrict__ src, const int* __restrict__ dst,
                       int* __restrict__ cur, int* __restrict__ srt, int nE) {
  int stride = gridDim.x * blockDim.x;
  for (int i = blockIdx.x * blockDim.x + threadIdx.x; i < nE; i += stride) {
    int d = dst[i];
    int p = atomicAdd(&cur[d], 1);
    srt[p] = src[i];
  }
}

// ---------------- readin: y[r,:] = x[r,:32] @ W(32x64) + b ----------------
__global__ void __launch_bounds__(256) k_readin(const float* __restrict__ x,
                                                const float* __restrict__ W,
                                                const float* __restrict__ b,
                                                float* __restrict__ y, int nRows) {
  __shared__ float Ws[2048];
  __shared__ float bs[64];
  for (int i = threadIdx.x; i < 2048; i += 256) Ws[i] = W[i];
  if (threadIdx.x < 64) bs[threadIdx.x] = b[threadIdx.x];
  __syncthreads();
  int lane = threadIdx.x & 63;
  int w = (blockIdx.x * blockDim.x + threadIdx.x) >> 6;
  int nw = (gridDim.x * blockDim.x) >> 6;
  for (int r = w; r < nRows; r += nw) {
    float v = x[(size_t)r * 32 + (lane & 31)];
    float acc = bs[lane];
#pragma unroll
    for (int i = 0; i < 32; i++) {
      float xi = __shfl(v, i, 64);
      acc = fmaf(xi, Ws[i * 64 + lane], acc);
    }
    y[(size_t)r * 64 + lane] = acc;
  }
}

// ---------------- BN stats: per-channel sum & sumsq ----------------
__global__ void __launch_bounds__(256) k_bnstats(const float* __restrict__ x,
                                                 float* __restrict__ gsum,
                                                 float* __restrict__ gsum2, int nRows) {
  int lane = threadIdx.x & 63;
  int wib = threadIdx.x >> 6;
  int w = blockIdx.x * 4 + wib;
  int nw = gridDim.x * 4;
  float s = 0.f, s2 = 0.f;
  for (int r = w; r < nRows; r += nw) {
    float v = x[(size_t)r * 64 + lane];
    s += v;
    s2 = fmaf(v, v, s2);
  }
  __shared__ float shs[4][64];
  __shared__ float shs2[4][64];
  shs[wib][lane] = s;
  shs2[wib][lane] = s2;
  __syncthreads();
  if (threadIdx.x < 64) {
    int c = threadIdx.x;
    float ts = shs[0][c] + shs[1][c] + shs[2][c] + shs[3][c];
    atomicAdd(&gsum[c], ts);
  } else if (threadIdx.x < 128) {
    int c = threadIdx.x & 63;
    float ts2 = shs2[0][c] + shs2[1][c] + shs2[2][c] + shs2[3][c];
    atomicAdd(&gsum2[c], ts2);
  }
}

// ---------------- BN finalize: scale/shift per channel, bus + gen ----------------
__global__ void k_bnfin(const float* __restrict__ stats,
                        const float* __restrict__ gamma_b, const float* __restrict__ beta_b,
                        const float* __restrict__ gamma_g, const float* __restrict__ beta_g,
                        float* __restrict__ ss) {
  int t = threadIdx.x;
  if (t < 64) {
    float m = stats[t] * (1.0f / NBUS);
    float m2 = stats[64 + t] * (1.0f / NBUS);
    float var = m2 - m * m;
    float rs = rsqrtf(var + 1e-5f);
    float sc = gamma_b[t] * rs;
    ss[t] = sc;
    ss[64 + t] = beta_b[t] - m * sc;
  } else if (t < 128) {
    int c = t - 64;
    float m = stats[128 + c] * (1.0f / NGEN);
    float m2 = stats[192 + c] * (1.0f / NGEN);
    float var = m2 - m * m;
    float rs = rsqrtf(var + 1e-5f);
    float sc = gamma_g[c] * rs;
    ss[128 + c] = sc;
    ss[192 + c] = beta_g[c] - m * sc;
  }
}

// ---------------- fused normalize + lrelu + tap0: c0 = y; x += y@W + b ----------------
__global__ void __launch_bounds__(256) k_norm_tap0(float* __restrict__ x,
                                                   float* __restrict__ c0,
                                                   const float* __restrict__ ss,
                                                   const float* __restrict__ W,
                                                   const float* __restrict__ b, int nRows) {
  __shared__ float Ws[4096];
  for (int i = threadIdx.x; i < 4096; i += 256) Ws[i] = W[i];
  __syncthreads();
  int lane = threadIdx.x & 63;
  float scale = ss[lane], shift = ss[64 + lane];
  float bv = b[lane];
  int w = (blockIdx.x * blockDim.x + threadIdx.x) >> 6;
  int nw = (gridDim.x * blockDim.x) >> 6;
  for (int r = w; r < nRows; r += nw) {
    size_t idx = (size_t)r * 64 + lane;
    float xv = x[idx];
    float y = fmaf(xv, scale, shift);
    y = (y >= 0.f) ? y : 0.01f * y;
    c0[idx] = y;
    float acc = bv;
#pragma unroll
    for (int i = 0; i < 64; i++) {
      float yi = __shfl(y, i, 64);
      acc = fmaf(yi, Ws[i * 64 + lane], acc);
    }
    x[idx] = xv + acc;
  }
}

// ---------------- fused shift (CSR pull, 2 edge sets) + tap GEMM ----------------
// n[d,:] = sum_{e in A(d)} cA[srcA,:] + sum_{e in B(d)} cB[srcB,:]
// x[d,:] += n[d,:] @ W + b
__global__ void __launch_bounds__(256) k_pull_tap(
    const int* __restrict__ offA, const int* __restrict__ srtA, const float* __restrict__ cA,
    const int* __restrict__ offB, const int* __restrict__ srtB, const float* __restrict__ cB,
    float* __restrict__ x, float* __restrict__ nout,
    const float* __restrict__ W, const float* __restrict__ b, int nRows) {
  __shared__ float Ws[4096];
  for (int i = threadIdx.x; i < 4096; i += 256) Ws[i] = W[i];
  __syncthreads();
  int lane = threadIdx.x & 63;
  float bv = b[lane];
  int w = (blockIdx.x * blockDim.x + threadIdx.x) >> 6;
  int nw = (gridDim.x * blockDim.x) >> 6;
  for (int r = w; r < nRows; r += nw) {
    float acc = 0.f;
    int beg = offA[r], end = offA[r + 1];
    for (int base = beg; base < end; base += 64) {
      int nn = end - base;
      if (nn > 64) nn = 64;
      int sl = (base + lane < end) ? srtA[base + lane] : 0;
      for (int j = 0; j < nn; j++) {
        int s = __shfl(sl, j, 64);
        acc += cA[(size_t)s * 64 + lane];
      }
    }
    if (offB) {
      int beg2 = offB[r], end2 = offB[r + 1];
      for (int e = beg2; e < end2; e++) {
        int s = srtB[e];
        acc += cB[(size_t)s * 64 + lane];
      }
    }
    size_t idx = (size_t)r * 64 + lane;
    nout[idx] = acc;
    float z = bv;
#pragma unroll
    for (int i = 0; i < 64; i++) {
      float ni = __shfl(acc, i, 64);
      z = fmaf(ni, Ws[i * 64 + lane], z);
    }
    x[idx] += z;
  }
}

// ---------------- readout: out[r,:32] = x[r,:64] @ W(64x32) + b ----------------
__global__ void __launch_bounds__(256) k_readout(const float* __restrict__ x,
                                                 const float* __restrict__ W,
                                                 const float* __restrict__ b,
                                                 float* __restrict__ out, int nRows) {
  __shared__ float Ws[2048];
  __shared__ float bs[32];
  for (int i = threadIdx.x; i < 2048; i += 256) Ws[i] = W[i];
  if (threadIdx.x < 32) bs[threadIdx.x] = b[threadIdx.x];
  __syncthreads();
  int lane = threadIdx.x & 63;
  int ch = lane & 31;
  int w = (blockIdx.x * blockDim.x + threadIdx.x) >> 6;
  int nw = (gridDim.x * blockDim.x) >> 6;
  for (int r = w; r < nRows; r += nw) {
    float v = x[(size_t)r * 64 + lane];
    float acc = bs[ch];
#pragma unroll
    for (int i = 0; i < 64; i++) {
      float xi = __shfl(v, i, 64);
      acc = fmaf(xi, Ws[i * 32 + ch], acc);
    }
    if (lane < 32) out[(size_t)r * 32 + ch] = acc;
  }
}

extern "C" void kernel_launch(void* const* d_in, const int* in_sizes, int n_in,
                              void* d_out, int out_size, void* d_ws, size_t ws_size,
                              hipStream_t stream) {
  const float* x_bus = (const float*)d_in[0];
  const float* x_gen = (const float*)d_in[1];
  const float* riWb = (const float*)d_in[2];
  const float* ribb = (const float*)d_in[3];
  const float* riWg = (const float*)d_in[4];
  const float* ribg = (const float*)d_in[5];
  const float* bng_b = (const float*)d_in[6];
  const float* bnb_b = (const float*)d_in[7];
  const float* bng_g = (const float*)d_in[8];
  const float* bnb_g = (const float*)d_in[9];
  const float* tWb = (const float*)d_in[10];
  const float* tbb = (const float*)d_in[11];
  const float* tWg = (const float*)d_in[12];
  const float* tbg = (const float*)d_in[13];
  const float* roWb = (const float*)d_in[14];
  const float* robb = (const float*)d_in[15];
  const float* roWg = (const float*)d_in[16];
  const float* robg = (const float*)d_in[17];
  const int* ebb = (const int*)d_in[18];
  const int* gb_src = (const int*)d_in[19];
  const int* gb_dst = (const int*)d_in[20];
  const int* bg_src = (const int*)d_in[21];
  const int* bg_dst = (const int*)d_in[22];
  const int* bb_src = ebb;
  const int* bb_dst = ebb + NEBB;

  // ---- workspace layout (256B aligned segments) ----
  char* p = (char*)d_ws;
  auto take = [&](size_t bytes) -> void* {
    void* r = (void*)p;
    p += (bytes + 255) & ~(size_t)255;
    return r;
  };
  float* xb = (float*)take((size_t)NBUS * 64 * 4);
  float* cb = (float*)take((size_t)NBUS * 64 * 4);
  float* nb = (float*)take((size_t)NBUS * 64 * 4);
  float* xg = (float*)take((size_t)NGEN * 64 * 4);
  float* cg = (float*)take((size_t)NGEN * 64 * 4);
  float* ng = (float*)take((size_t)NGEN * 64 * 4);
  int* bb_off = (int*)take((size_t)(NBUS + 1) * 4);
  int* bb_cur = (int*)take((size_t)NBUS * 4);
  int* bb_srt = (int*)take((size_t)NEBB * 4);
  int* gb_off = (int*)take((size_t)(NBUS + 1) * 4);
  int* gb_cur = (int*)take((size_t)NBUS * 4);
  int* gb_srt = (int*)take((size_t)NEGB * 4);
  int* bg_off = (int*)take((size_t)(NGEN + 1) * 4);
  int* bg_cur = (int*)take((size_t)NGEN * 4);
  int* bg_srt = (int*)take((size_t)NEBG * 4);
  int* bsums = (int*)take(256 * 4);
  float* stats = (float*)take(256 * 4);
  float* ss = (float*)take(256 * 4);
  if ((size_t)(p - (char*)d_ws) > ws_size) return;  // ws too small -> visible validation failure

  // ---- CSR build (once per launch; reused by all 8 shifts) ----
  hipMemsetAsync(bb_cur, 0, (size_t)NBUS * 4, stream);
  hipMemsetAsync(gb_cur, 0, (size_t)NBUS * 4, stream);
  hipMemsetAsync(bg_cur, 0, (size_t)NGEN * 4, stream);

  k_hist<<<2048, 256, 0, stream>>>(bb_dst, bb_cur, NEBB);
  k_hist<<<256, 256, 0, stream>>>(gb_dst, gb_cur, NEGB);
  k_hist<<<256, 256, 0, stream>>>(bg_dst, bg_cur, NEBG);

  k_scan1<<<128, 256, 0, stream>>>(bb_cur, bb_off, bsums, NBUS);
  k_scan2<<<1, 256, 0, stream>>>(bsums, 128);
  k_scan3<<<512, 256, 0, stream>>>(bb_off, bb_cur, bsums, NBUS, NEBB);

  k_scan1<<<128, 256, 0, stream>>>(gb_cur, gb_off, bsums, NBUS);
  k_scan2<<<1, 256, 0, stream>>>(bsums, 128);
  k_scan3<<<512, 256, 0, stream>>>(gb_off, gb_cur, bsums, NBUS, NEGB);

  k_scan1<<<32, 256, 0, stream>>>(bg_cur, bg_off, bsums, NGEN);
  k_scan2<<<1, 256, 0, stream>>>(bsums, 32);
  k_scan3<<<128, 256, 0, stream>>>(bg_off, bg_cur, bsums, NGEN, NEBG);

  k_fill<<<2048, 256, 0, stream>>>(bb_src, bb_dst, bb_cur, bb_srt, NEBB);
  k_fill<<<256, 256, 0, stream>>>(gb_src, gb_dst, gb_cur, gb_srt, NEGB);
  k_fill<<<256, 256, 0, stream>>>(bg_src, bg_dst, bg_cur, bg_srt, NEBG);

  // ---- readin ----
  k_readin<<<4096, 256, 0, stream>>>(x_bus, riWb, ribb, xb, NBUS);
  k_readin<<<1024, 256, 0, stream>>>(x_gen, riWg, ribg, xg, NGEN);

  // ---- residual blocks ----
  float *cbp = cb, *nbp = nb, *cgp = cg, *ngp = ng;
  for (int l = 0; l < 2; l++) {
    hipMemsetAsync(stats, 0, 256 * 4, stream);
    k_bnstats<<<512, 256, 0, stream>>>(xb, stats, stats + 64, NBUS);
    k_bnstats<<<128, 256, 0, stream>>>(xg, stats + 128, stats + 192, NGEN);
    k_bnfin<<<1, 128, 0, stream>>>(stats, bng_b + l * 64, bnb_b + l * 64,
                                   bng_g + l * 64, bnb_g + l * 64, ss);
    k_norm_tap0<<<4096, 256, 0, stream>>>(xb, cbp, ss, tWb + (size_t)(l * 5) * 4096,
                                          tbb + (size_t)(l * 5) * 64, NBUS);
    k_norm_tap0<<<1024, 256, 0, stream>>>(xg, cgp, ss + 128, tWg + (size_t)(l * 5) * 4096,
                                          tbg + (size_t)(l * 5) * 64, NGEN);
    for (int k = 1; k < 5; k++) {
      k_pull_tap<<<4096, 256, 0, stream>>>(bb_off, bb_srt, cbp, gb_off, gb_srt, cgp,
                                           xb, nbp, tWb + (size_t)(l * 5 + k) * 4096,
                                           tbb + (size_t)(l * 5 + k) * 64, NBUS);
      k_pull_tap<<<1024, 256, 0, stream>>>(bg_off, bg_srt, cbp,
                                           (const int*)nullptr, (const int*)nullptr,
                                           (const float*)nullptr,
                                           xg, ngp, tWg + (size_t)(l * 5 + k) * 4096,
                                           tbg + (size_t)(l * 5 + k) * 64, NGEN);
      float* t;
      t = cbp; cbp = nbp; nbp = t;
      t = cgp; cgp = ngp; ngp = t;
    }
  }

  // ---- readout ----
  k_readout<<<4096, 256, 0, stream>>>(xb, roWb, robb, (float*)d_out, NBUS);
  k_readout<<<1024, 256, 0, stream>>>(xg, roWg, robg, (float*)d_out + (size_t)NBUS * 32, NGEN);
}

// Round 2
// 2688.552 us; speedup vs baseline: 1.2485x; 1.2485x over previous
//
#include <hip/hip_runtime.h>

#define NBUS 131072
#define NGEN 32768
#define NEBB 2097152
#define NEGB 65536
#define NEBG 65536

typedef float f32x2 __attribute__((ext_vector_type(2)));

// ---------------- CSR build ----------------
__global__ void k_hist(const int* __restrict__ dst, int* __restrict__ counts, int nE) {
  int stride = gridDim.x * blockDim.x;
  for (int i = blockIdx.x * blockDim.x + threadIdx.x; i < nE; i += stride)
    atomicAdd(&counts[dst[i]], 1);
}

// per-block tile (1024 elems) exclusive scan; bsums[b] = tile total
__global__ void k_scan1(const int* __restrict__ in, int* __restrict__ out,
                        int* __restrict__ bsums, int n) {
  __shared__ int sh[256];
  int t = threadIdx.x;
  int base = blockIdx.x * 1024 + t * 4;
  int v0 = (base + 0 < n) ? in[base + 0] : 0;
  int v1 = (base + 1 < n) ? in[base + 1] : 0;
  int v2 = (base + 2 < n) ? in[base + 2] : 0;
  int v3 = (base + 3 < n) ? in[base + 3] : 0;
  int t0 = v0, t1 = t0 + v1, t2 = t1 + v2, t3 = t2 + v3;
  sh[t] = t3;
  __syncthreads();
  for (int off = 1; off < 256; off <<= 1) {
    int x = (t >= off) ? sh[t - off] : 0;
    __syncthreads();
    sh[t] += x;
    __syncthreads();
  }
  int excl = (t > 0) ? sh[t - 1] : 0;
  if (base + 0 < n) out[base + 0] = excl;
  if (base + 1 < n) out[base + 1] = excl + t0;
  if (base + 2 < n) out[base + 2] = excl + t1;
  if (base + 3 < n) out[base + 3] = excl + t2;
  if (t == 255) bsums[blockIdx.x] = sh[255];
}

// single-block exclusive scan of block sums (nb <= 256)
__global__ void k_scan2(int* __restrict__ bsums, int nb) {
  __shared__ int sh[256];
  int t = threadIdx.x;
  int v = (t < nb) ? bsums[t] : 0;
  sh[t] = v;
  __syncthreads();
  for (int off = 1; off < 256; off <<= 1) {
    int x = (t >= off) ? sh[t - off] : 0;
    __syncthreads();
    sh[t] += x;
    __syncthreads();
  }
  int excl = (t > 0) ? sh[t - 1] : 0;
  if (t < nb) bsums[t] = excl;
}

// add block offsets; copy result into cursor; write offsets[n] = E
__global__ void k_scan3(int* __restrict__ off, int* __restrict__ cur,
                        const int* __restrict__ bsums, int n, int E) {
  int stride = gridDim.x * blockDim.x;
  for (int i = blockIdx.x * blockDim.x + threadIdx.x; i < n; i += stride) {
    int o = off[i] + bsums[i >> 10];
    off[i] = o;
    cur[i] = o;
  }
  if (blockIdx.x == 0 && threadIdx.x == 0) off[n] = E;
}

__global__ void k_fill(const int* __restrict__ src, const int* __restrict__ dst,
                       int* __restrict__ cur, int* __restrict__ srt, int nE) {
  int stride = gridDim.x * blockDim.x;
  for (int i = blockIdx.x * blockDim.x + threadIdx.x; i < nE; i += stride) {
    int d = dst[i];
    int p = atomicAdd(&cur[d], 1);
    srt[p] = src[i];
  }
}

// ---------------- readin: y[r,:] = x[r,:32] @ W(32x64) + b ----------------
__global__ void __launch_bounds__(256) k_readin(const float* __restrict__ x,
                                                const float* __restrict__ W,
                                                const float* __restrict__ b,
                                                float* __restrict__ y, int nRows) {
  __shared__ float Ws[2048];
  __shared__ float bs[64];
  for (int i = threadIdx.x; i < 2048; i += 256) Ws[i] = W[i];
  if (threadIdx.x < 64) bs[threadIdx.x] = b[threadIdx.x];
  __syncthreads();
  int lane = threadIdx.x & 63;
  int w = (blockIdx.x * blockDim.x + threadIdx.x) >> 6;
  int nw = (gridDim.x * blockDim.x) >> 6;
  for (int r = w; r < nRows; r += nw) {
    float v = x[(size_t)r * 32 + (lane & 31)];
    float acc = bs[lane];
#pragma unroll
    for (int i = 0; i < 32; i++) {
      float xi = __shfl(v, i, 64);
      acc = fmaf(xi, Ws[i * 64 + lane], acc);
    }
    y[(size_t)r * 64 + lane] = acc;
  }
}

// ---------------- BN stats: per-channel sum & sumsq ----------------
__global__ void __launch_bounds__(256) k_bnstats(const float* __restrict__ x,
                                                 float* __restrict__ gsum,
                                                 float* __restrict__ gsum2, int nRows) {
  int lane = threadIdx.x & 63;
  int wib = threadIdx.x >> 6;
  int w = blockIdx.x * 4 + wib;
  int nw = gridDim.x * 4;
  float s = 0.f, s2 = 0.f;
  for (int r = w; r < nRows; r += nw) {
    float v = x[(size_t)r * 64 + lane];
    s += v;
    s2 = fmaf(v, v, s2);
  }
  __shared__ float shs[4][64];
  __shared__ float shs2[4][64];
  shs[wib][lane] = s;
  shs2[wib][lane] = s2;
  __syncthreads();
  if (threadIdx.x < 64) {
    int c = threadIdx.x;
    float ts = shs[0][c] + shs[1][c] + shs[2][c] + shs[3][c];
    atomicAdd(&gsum[c], ts);
  } else if (threadIdx.x < 128) {
    int c = threadIdx.x & 63;
    float ts2 = shs2[0][c] + shs2[1][c] + shs2[2][c] + shs2[3][c];
    atomicAdd(&gsum2[c], ts2);
  }
}

// ---------------- BN finalize: scale/shift per channel, bus + gen ----------------
__global__ void k_bnfin(const float* __restrict__ stats,
                        const float* __restrict__ gamma_b, const float* __restrict__ beta_b,
                        const float* __restrict__ gamma_g, const float* __restrict__ beta_g,
                        float* __restrict__ ss) {
  int t = threadIdx.x;
  if (t < 64) {
    float m = stats[t] * (1.0f / NBUS);
    float m2 = stats[64 + t] * (1.0f / NBUS);
    float var = m2 - m * m;
    float rs = rsqrtf(var + 1e-5f);
    float sc = gamma_b[t] * rs;
    ss[t] = sc;
    ss[64 + t] = beta_b[t] - m * sc;
  } else if (t < 128) {
    int c = t - 64;
    float m = stats[128 + c] * (1.0f / NGEN);
    float m2 = stats[192 + c] * (1.0f / NGEN);
    float var = m2 - m * m;
    float rs = rsqrtf(var + 1e-5f);
    float sc = gamma_g[c] * rs;
    ss[128 + c] = sc;
    ss[192 + c] = beta_g[c] - m * sc;
  }
}

// ---------------- fused normalize + lrelu + tap0: c0 = y; x += y@W + b ----------------
__global__ void __launch_bounds__(256) k_norm_tap0(float* __restrict__ x,
                                                   float* __restrict__ c0,
                                                   const float* __restrict__ ss,
                                                   const float* __restrict__ W,
                                                   const float* __restrict__ b, int nRows) {
  __shared__ float Ws[4096];
  for (int i = threadIdx.x; i < 4096; i += 256) Ws[i] = W[i];
  __syncthreads();
  int lane = threadIdx.x & 63;
  float scale = ss[lane], shift = ss[64 + lane];
  float bv = b[lane];
  int w = (blockIdx.x * blockDim.x + threadIdx.x) >> 6;
  int nw = (gridDim.x * blockDim.x) >> 6;
  for (int r = w; r < nRows; r += nw) {
    size_t idx = (size_t)r * 64 + lane;
    float xv = __builtin_nontemporal_load(&x[idx]);
    float y = fmaf(xv, scale, shift);
    y = (y >= 0.f) ? y : 0.01f * y;
    c0[idx] = y;  // cached: gather source for next shift
    float acc = bv;
#pragma unroll
    for (int i = 0; i < 64; i++) {
      float yi = __shfl(y, i, 64);
      acc = fmaf(yi, Ws[i * 64 + lane], acc);
    }
    __builtin_nontemporal_store(xv + acc, &x[idx]);
  }
}

// ---------------- fused shift (CSR pull, 2 edge sets) + tap GEMM ----------------
// Two dest rows per wave (half-wave each, 2 channels/lane as float2),
// 4-way unrolled accumulators -> up to 8 outstanding gather loads per wave.
__global__ void __launch_bounds__(256) k_pull_tap(
    const int* __restrict__ offA, const int* __restrict__ srtA, const float* __restrict__ cA,
    const int* __restrict__ offB, const int* __restrict__ srtB, const float* __restrict__ cB,
    float* __restrict__ x, float* __restrict__ nout,
    const float* __restrict__ W, const float* __restrict__ b, int nRows) {
  __shared__ float Ws[4096];
  for (int i = threadIdx.x; i < 4096; i += 256) Ws[i] = W[i];
  __syncthreads();
  const int lane = threadIdx.x & 63;
  const int half = lane >> 5;   // which row of the pair this lane serves
  const int sub = lane & 31;    // channel-pair index within the row
  const int c0 = sub * 2;
  const int h32 = half * 32;
  const f32x2 bv = *(const f32x2*)&b[c0];
  int w = (blockIdx.x * blockDim.x + threadIdx.x) >> 6;
  int nw = (gridDim.x * blockDim.x) >> 6;
  int nPairs = nRows >> 1;
  for (int pr = w; pr < nPairs; pr += nw) {
    int r = pr * 2 + half;
    f32x2 a0 = {0.f, 0.f}, a1 = {0.f, 0.f}, a2 = {0.f, 0.f}, a3 = {0.f, 0.f};
    int beg = offA[r], end = offA[r + 1];
    for (int base = beg; base < end; base += 32) {
      int sl = (base + sub < end) ? srtA[base + sub] : 0;
      int nn = end - base;
      if (nn > 32) nn = 32;
      int j = 0;
      for (; j + 4 <= nn; j += 4) {
        int s0 = __shfl(sl, h32 + j + 0, 64);
        int s1 = __shfl(sl, h32 + j + 1, 64);
        int s2 = __shfl(sl, h32 + j + 2, 64);
        int s3 = __shfl(sl, h32 + j + 3, 64);
        f32x2 v0 = *(const f32x2*)&cA[(size_t)s0 * 64 + c0];
        f32x2 v1 = *(const f32x2*)&cA[(size_t)s1 * 64 + c0];
        f32x2 v2 = *(const f32x2*)&cA[(size_t)s2 * 64 + c0];
        f32x2 v3 = *(const f32x2*)&cA[(size_t)s3 * 64 + c0];
        a0 += v0;
        a1 += v1;
        a2 += v2;
        a3 += v3;
      }
      for (; j < nn; j++) {
        int s = __shfl(sl, h32 + j, 64);
        a0 += *(const f32x2*)&cA[(size_t)s * 64 + c0];
      }
    }
    if (offB) {
      int beg2 = offB[r], end2 = offB[r + 1];
      for (int e = beg2; e < end2; e++) {
        int s = srtB[e];
        a0 += *(const f32x2*)&cB[(size_t)s * 64 + c0];
      }
    }
    f32x2 acc = (a0 + a1) + (a2 + a3);
    size_t idx = (size_t)r * 64 + c0;
    *(f32x2*)&nout[idx] = acc;  // cached: gather source for next shift
    float zx = bv.x, zy = bv.y;
#pragma unroll
    for (int t = 0; t < 32; ++t) {
      float nx = __shfl(acc.x, h32 + t, 64);
      float ny = __shfl(acc.y, h32 + t, 64);
      f32x2 w0 = *(const f32x2*)&Ws[(2 * t) * 64 + c0];
      f32x2 w1 = *(const f32x2*)&Ws[(2 * t + 1) * 64 + c0];
      zx = fmaf(nx, w0.x, zx);
      zy = fmaf(nx, w0.y, zy);
      zx = fmaf(ny, w1.x, zx);
      zy = fmaf(ny, w1.y, zy);
    }
    f32x2 xv = __builtin_nontemporal_load((const f32x2*)&x[idx]);
    f32x2 xo = {xv.x + zx, xv.y + zy};
    __builtin_nontemporal_store(xo, (f32x2*)&x[idx]);
  }
}

// ---------------- readout: out[r,:32] = x[r,:64] @ W(64x32) + b ----------------
__global__ void __launch_bounds__(256) k_readout(const float* __restrict__ x,
                                                 const float* __restrict__ W,
                                                 const float* __restrict__ b,
                                                 float* __restrict__ out, int nRows) {
  __shared__ float Ws[2048];
  __shared__ float bs[32];
  for (int i = threadIdx.x; i < 2048; i += 256) Ws[i] = W[i];
  if (threadIdx.x < 32) bs[threadIdx.x] = b[threadIdx.x];
  __syncthreads();
  int lane = threadIdx.x & 63;
  int ch = lane & 31;
  int w = (blockIdx.x * blockDim.x + threadIdx.x) >> 6;
  int nw = (gridDim.x * blockDim.x) >> 6;
  for (int r = w; r < nRows; r += nw) {
    float v = x[(size_t)r * 64 + lane];
    float acc = bs[ch];
#pragma unroll
    for (int i = 0; i < 64; i++) {
      float xi = __shfl(v, i, 64);
      acc = fmaf(xi, Ws[i * 32 + ch], acc);
    }
    if (lane < 32) out[(size_t)r * 32 + ch] = acc;
  }
}

extern "C" void kernel_launch(void* const* d_in, const int* in_sizes, int n_in,
                              void* d_out, int out_size, void* d_ws, size_t ws_size,
                              hipStream_t stream) {
  const float* x_bus = (const float*)d_in[0];
  const float* x_gen = (const float*)d_in[1];
  const float* riWb = (const float*)d_in[2];
  const float* ribb = (const float*)d_in[3];
  const float* riWg = (const float*)d_in[4];
  const float* ribg = (const float*)d_in[5];
  const float* bng_b = (const float*)d_in[6];
  const float* bnb_b = (const float*)d_in[7];
  const float* bng_g = (const float*)d_in[8];
  const float* bnb_g = (const float*)d_in[9];
  const float* tWb = (const float*)d_in[10];
  const float* tbb = (const float*)d_in[11];
  const float* tWg = (const float*)d_in[12];
  const float* tbg = (const float*)d_in[13];
  const float* roWb = (const float*)d_in[14];
  const float* robb = (const float*)d_in[15];
  const float* roWg = (const float*)d_in[16];
  const float* robg = (const float*)d_in[17];
  const int* ebb = (const int*)d_in[18];
  const int* gb_src = (const int*)d_in[19];
  const int* gb_dst = (const int*)d_in[20];
  const int* bg_src = (const int*)d_in[21];
  const int* bg_dst = (const int*)d_in[22];
  const int* bb_src = ebb;
  const int* bb_dst = ebb + NEBB;

  // ---- workspace layout (256B aligned segments) ----
  char* p = (char*)d_ws;
  auto take = [&](size_t bytes) -> void* {
    void* r = (void*)p;
    p += (bytes + 255) & ~(size_t)255;
    return r;
  };
  float* xb = (float*)take((size_t)NBUS * 64 * 4);
  float* cb = (float*)take((size_t)NBUS * 64 * 4);
  float* nb = (float*)take((size_t)NBUS * 64 * 4);
  float* xg = (float*)take((size_t)NGEN * 64 * 4);
  float* cg = (float*)take((size_t)NGEN * 64 * 4);
  float* ng = (float*)take((size_t)NGEN * 64 * 4);
  int* bb_off = (int*)take((size_t)(NBUS + 1) * 4);
  int* bb_cur = (int*)take((size_t)NBUS * 4);
  int* bb_srt = (int*)take((size_t)NEBB * 4);
  int* gb_off = (int*)take((size_t)(NBUS + 1) * 4);
  int* gb_cur = (int*)take((size_t)NBUS * 4);
  int* gb_srt = (int*)take((size_t)NEGB * 4);
  int* bg_off = (int*)take((size_t)(NGEN + 1) * 4);
  int* bg_cur = (int*)take((size_t)NGEN * 4);
  int* bg_srt = (int*)take((size_t)NEBG * 4);
  int* bsums = (int*)take(256 * 4);
  float* stats = (float*)take(256 * 4);
  float* ss = (float*)take(256 * 4);
  if ((size_t)(p - (char*)d_ws) > ws_size) return;  // ws too small -> visible validation failure

  // ---- CSR build (once per launch; reused by all 8 shifts) ----
  hipMemsetAsync(bb_cur, 0, (size_t)NBUS * 4, stream);
  hipMemsetAsync(gb_cur, 0, (size_t)NBUS * 4, stream);
  hipMemsetAsync(bg_cur, 0, (size_t)NGEN * 4, stream);

  k_hist<<<2048, 256, 0, stream>>>(bb_dst, bb_cur, NEBB);
  k_hist<<<256, 256, 0, stream>>>(gb_dst, gb_cur, NEGB);
  k_hist<<<256, 256, 0, stream>>>(bg_dst, bg_cur, NEBG);

  k_scan1<<<128, 256, 0, stream>>>(bb_cur, bb_off, bsums, NBUS);
  k_scan2<<<1, 256, 0, stream>>>(bsums, 128);
  k_scan3<<<512, 256, 0, stream>>>(bb_off, bb_cur, bsums, NBUS, NEBB);

  k_scan1<<<128, 256, 0, stream>>>(gb_cur, gb_off, bsums, NBUS);
  k_scan2<<<1, 256, 0, stream>>>(bsums, 128);
  k_scan3<<<512, 256, 0, stream>>>(gb_off, gb_cur, bsums, NBUS, NEGB);

  k_scan1<<<32, 256, 0, stream>>>(bg_cur, bg_off, bsums, NGEN);
  k_scan2<<<1, 256, 0, stream>>>(bsums, 32);
  k_scan3<<<128, 256, 0, stream>>>(bg_off, bg_cur, bsums, NGEN, NEBG);

  k_fill<<<2048, 256, 0, stream>>>(bb_src, bb_dst, bb_cur, bb_srt, NEBB);
  k_fill<<<256, 256, 0, stream>>>(gb_src, gb_dst, gb_cur, gb_srt, NEGB);
  k_fill<<<256, 256, 0, stream>>>(bg_src, bg_dst, bg_cur, bg_srt, NEBG);

  // ---- readin ----
  k_readin<<<4096, 256, 0, stream>>>(x_bus, riWb, ribb, xb, NBUS);
  k_readin<<<1024, 256, 0, stream>>>(x_gen, riWg, ribg, xg, NGEN);

  // ---- residual blocks ----
  float *cbp = cb, *nbp = nb, *cgp = cg, *ngp = ng;
  for (int l = 0; l < 2; l++) {
    hipMemsetAsync(stats, 0, 256 * 4, stream);
    k_bnstats<<<512, 256, 0, stream>>>(xb, stats, stats + 64, NBUS);
    k_bnstats<<<128, 256, 0, stream>>>(xg, stats + 128, stats + 192, NGEN);
    k_bnfin<<<1, 128, 0, stream>>>(stats, bng_b + l * 64, bnb_b + l * 64,
                                   bng_g + l * 64, bnb_g + l * 64, ss);
    k_norm_tap0<<<4096, 256, 0, stream>>>(xb, cbp, ss, tWb + (size_t)(l * 5) * 4096,
                                          tbb + (size_t)(l * 5) * 64, NBUS);
    k_norm_tap0<<<1024, 256, 0, stream>>>(xg, cgp, ss + 128, tWg + (size_t)(l * 5) * 4096,
                                          tbg + (size_t)(l * 5) * 64, NGEN);
    for (int k = 1; k < 5; k++) {
      k_pull_tap<<<4096, 256, 0, stream>>>(bb_off, bb_srt, cbp, gb_off, gb_srt, cgp,
                                           xb, nbp, tWb + (size_t)(l * 5 + k) * 4096,
                                           tbb + (size_t)(l * 5 + k) * 64, NBUS);
      k_pull_tap<<<1024, 256, 0, stream>>>(bg_off, bg_srt, cbp,
                                           (const int*)nullptr, (const int*)nullptr,
                                           (const float*)nullptr,
                                           xg, ngp, tWg + (size_t)(l * 5 + k) * 4096,
                                           tbg + (size_t)(l * 5 + k) * 64, NGEN);
      float* t;
      t = cbp; cbp = nbp; nbp = t;
      t = cgp; cgp = ngp; ngp = t;
    }
  }

  // ---- readout ----
  k_readout<<<4096, 256, 0, stream>>>(xb, roWb, robb, (float*)d_out, NBUS);
  k_readout<<<1024, 256, 0, stream>>>(xg, roWg, robg, (float*)d_out + (size_t)NBUS * 32, NGEN);
}

// Round 3
// 2477.012 us; speedup vs baseline: 1.3551x; 1.0854x over previous
//
#include <hip/hip_runtime.h>

#define NBUS 131072
#define NGEN 32768
#define NEBB 2097152
#define NEGB 65536
#define NEBG 65536
#define NEBUS (NEBB + NEGB)  // merged bus-dest CSR (bb + gb)

typedef float f32x2 __attribute__((ext_vector_type(2)));

// ---------------- CSR build ----------------
__global__ void k_hist(const int* __restrict__ dst, int* __restrict__ counts, int nE) {
  int stride = gridDim.x * blockDim.x;
  for (int i = blockIdx.x * blockDim.x + threadIdx.x; i < nE; i += stride)
    atomicAdd(&counts[dst[i]], 1);
}

__global__ void k_scan1(const int* __restrict__ in, int* __restrict__ out,
                        int* __restrict__ bsums, int n) {
  __shared__ int sh[256];
  int t = threadIdx.x;
  int base = blockIdx.x * 1024 + t * 4;
  int v0 = (base + 0 < n) ? in[base + 0] : 0;
  int v1 = (base + 1 < n) ? in[base + 1] : 0;
  int v2 = (base + 2 < n) ? in[base + 2] : 0;
  int v3 = (base + 3 < n) ? in[base + 3] : 0;
  int t0 = v0, t1 = t0 + v1, t2 = t1 + v2, t3 = t2 + v3;
  sh[t] = t3;
  __syncthreads();
  for (int off = 1; off < 256; off <<= 1) {
    int x = (t >= off) ? sh[t - off] : 0;
    __syncthreads();
    sh[t] += x;
    __syncthreads();
  }
  int excl = (t > 0) ? sh[t - 1] : 0;
  if (base + 0 < n) out[base + 0] = excl;
  if (base + 1 < n) out[base + 1] = excl + t0;
  if (base + 2 < n) out[base + 2] = excl + t1;
  if (base + 3 < n) out[base + 3] = excl + t2;
  if (t == 255) bsums[blockIdx.x] = sh[255];
}

__global__ void k_scan2(int* __restrict__ bsums, int nb) {
  __shared__ int sh[256];
  int t = threadIdx.x;
  int v = (t < nb) ? bsums[t] : 0;
  sh[t] = v;
  __syncthreads();
  for (int off = 1; off < 256; off <<= 1) {
    int x = (t >= off) ? sh[t - off] : 0;
    __syncthreads();
    sh[t] += x;
    __syncthreads();
  }
  int excl = (t > 0) ? sh[t - 1] : 0;
  if (t < nb) bsums[t] = excl;
}

__global__ void k_scan3(int* __restrict__ off, int* __restrict__ cur,
                        const int* __restrict__ bsums, int n, int E) {
  int stride = gridDim.x * blockDim.x;
  for (int i = blockIdx.x * blockDim.x + threadIdx.x; i < n; i += stride) {
    int o = off[i] + bsums[i >> 10];
    off[i] = o;
    cur[i] = o;
  }
  if (blockIdx.x == 0 && threadIdx.x == 0) off[n] = E;
}

// srcOff encodes the source-feature section (gen rows live at NBUS+src)
__global__ void k_fill(const int* __restrict__ src, const int* __restrict__ dst,
                       int* __restrict__ cur, int* __restrict__ srt, int nE, int srcOff) {
  int stride = gridDim.x * blockDim.x;
  for (int i = blockIdx.x * blockDim.x + threadIdx.x; i < nE; i += stride) {
    int d = dst[i];
    int p = atomicAdd(&cur[d], 1);
    srt[p] = src[i] + srcOff;
  }
}

// ---------------- readin + fused BN-stats ----------------
__global__ void __launch_bounds__(256) k_readin(const float* __restrict__ x,
                                                const float* __restrict__ W,
                                                const float* __restrict__ b,
                                                float* __restrict__ y, int nRows,
                                                float* __restrict__ stats) {
  __shared__ float Ws[2048];
  __shared__ float bs[64];
  __shared__ float shs[4][64];
  __shared__ float shs2[4][64];
  for (int i = threadIdx.x; i < 2048; i += 256) Ws[i] = W[i];
  if (threadIdx.x < 64) bs[threadIdx.x] = b[threadIdx.x];
  __syncthreads();
  int lane = threadIdx.x & 63;
  int wib = threadIdx.x >> 6;
  int w = (blockIdx.x * blockDim.x + threadIdx.x) >> 6;
  int nw = (gridDim.x * blockDim.x) >> 6;
  float ls = 0.f, ls2 = 0.f;
  for (int r = w; r < nRows; r += nw) {
    float v = x[(size_t)r * 32 + (lane & 31)];
    float acc = bs[lane];
#pragma unroll
    for (int i = 0; i < 32; i++) {
      float xi = __shfl(v, i, 64);
      acc = fmaf(xi, Ws[i * 64 + lane], acc);
    }
    y[(size_t)r * 64 + lane] = acc;
    ls += acc;
    ls2 = fmaf(acc, acc, ls2);
  }
  shs[wib][lane] = ls;
  shs2[wib][lane] = ls2;
  __syncthreads();
  if (threadIdx.x < 64) {
    int c = threadIdx.x;
    atomicAdd(&stats[c], shs[0][c] + shs[1][c] + shs[2][c] + shs[3][c]);
  } else if (threadIdx.x < 128) {
    int c = threadIdx.x & 63;
    atomicAdd(&stats[64 + c], shs2[0][c] + shs2[1][c] + shs2[2][c] + shs2[3][c]);
  }
}

// ---------------- fused BN-finalize + normalize + lrelu + tap0 ----------------
__global__ void __launch_bounds__(256) k_norm_tap0(float* __restrict__ x,
                                                   float* __restrict__ c0,
                                                   const float* __restrict__ stats, float invN,
                                                   const float* __restrict__ gamma,
                                                   const float* __restrict__ beta,
                                                   const float* __restrict__ W,
                                                   const float* __restrict__ b, int nRows) {
  __shared__ float Ws[4096];
  for (int i = threadIdx.x; i < 4096; i += 256) Ws[i] = W[i];
  __syncthreads();
  int lane = threadIdx.x & 63;
  float m = stats[lane] * invN;
  float m2 = stats[64 + lane] * invN;
  float rs = rsqrtf(m2 - m * m + 1e-5f);
  float scale = gamma[lane] * rs;
  float shift = beta[lane] - m * scale;
  float bv = b[lane];
  int w = (blockIdx.x * blockDim.x + threadIdx.x) >> 6;
  int nw = (gridDim.x * blockDim.x) >> 6;
  for (int r = w; r < nRows; r += nw) {
    size_t idx = (size_t)r * 64 + lane;
    float xv = __builtin_nontemporal_load(&x[idx]);
    float y = fmaf(xv, scale, shift);
    y = (y >= 0.f) ? y : 0.01f * y;
    c0[idx] = y;  // cached: gather source for next shift
    float acc = bv;
#pragma unroll
    for (int i = 0; i < 64; i++) {
      float yi = __shfl(y, i, 64);
      acc = fmaf(yi, Ws[i * 64 + lane], acc);
    }
    __builtin_nontemporal_store(xv + acc, &x[idx]);
  }
}

// ---------------- fused shift (merged CSR pull) + tap GEMM + optional BN-stats ----------------
// Two dest rows per wave (half-wave each, 2 channels/lane as float2).
// 8 gather loads in flight per wave; next-pair offsets and first srt chunk
// prefetched under the GEMM phase.
__global__ void __launch_bounds__(256) k_pull_tap(
    const int* __restrict__ off, const int* __restrict__ srt,
    const float* __restrict__ call,
    float* __restrict__ x, float* __restrict__ nout,
    const float* __restrict__ W, const float* __restrict__ b,
    int nRows, float* __restrict__ stats) {
  __shared__ float Ws[4096];
  __shared__ f32x2 shS[256];
  __shared__ f32x2 shS2[256];
  for (int i = threadIdx.x; i < 4096; i += 256) Ws[i] = W[i];
  __syncthreads();
  const int lane = threadIdx.x & 63;
  const int half = lane >> 5;
  const int sub = lane & 31;
  const int c0 = sub * 2;
  const int h32 = half * 32;
  const f32x2 bv = *(const f32x2*)&b[c0];
  f32x2 ls = {0.f, 0.f}, ls2 = {0.f, 0.f};
  int w = (blockIdx.x * blockDim.x + threadIdx.x) >> 6;
  int nw = (gridDim.x * blockDim.x) >> 6;
  int nPairs = nRows >> 1;
  int begN = 0, endN = 0, slN = 0;
  if (w < nPairs) {
    int rN = w * 2 + half;
    begN = off[rN];
    endN = off[rN + 1];
    slN = (begN + sub < endN) ? srt[begN + sub] : 0;
  }
  for (int pr = w; pr < nPairs; pr += nw) {
    int r = pr * 2 + half;
    int beg = begN, end = endN;
    int sl_cur = slN;
    int prn = pr + nw;
    if (prn < nPairs) {  // prefetch next pair's offsets (used after gather)
      int rn = prn * 2 + half;
      begN = off[rn];
      endN = off[rn + 1];
    }
    f32x2 a0 = {0.f, 0.f}, a1 = {0.f, 0.f}, a2 = {0.f, 0.f}, a3 = {0.f, 0.f};
    for (int base = beg; base < end; base += 32) {
      int nn = end - base;
      if (nn > 32) nn = 32;
      int sl_nx = 0;
      if (base + 32 < end)  // prefetch next chunk's srt
        sl_nx = (base + 32 + sub < end) ? srt[base + 32 + sub] : 0;
      int j = 0;
      for (; j + 8 <= nn; j += 8) {
        int s0 = __shfl(sl_cur, h32 + j + 0, 64);
        int s1 = __shfl(sl_cur, h32 + j + 1, 64);
        int s2 = __shfl(sl_cur, h32 + j + 2, 64);
        int s3 = __shfl(sl_cur, h32 + j + 3, 64);
        int s4 = __shfl(sl_cur, h32 + j + 4, 64);
        int s5 = __shfl(sl_cur, h32 + j + 5, 64);
        int s6 = __shfl(sl_cur, h32 + j + 6, 64);
        int s7 = __shfl(sl_cur, h32 + j + 7, 64);
        f32x2 v0 = *(const f32x2*)&call[(size_t)s0 * 64 + c0];
        f32x2 v1 = *(const f32x2*)&call[(size_t)s1 * 64 + c0];
        f32x2 v2 = *(const f32x2*)&call[(size_t)s2 * 64 + c0];
        f32x2 v3 = *(const f32x2*)&call[(size_t)s3 * 64 + c0];
        f32x2 v4 = *(const f32x2*)&call[(size_t)s4 * 64 + c0];
        f32x2 v5 = *(const f32x2*)&call[(size_t)s5 * 64 + c0];
        f32x2 v6 = *(const f32x2*)&call[(size_t)s6 * 64 + c0];
        f32x2 v7 = *(const f32x2*)&call[(size_t)s7 * 64 + c0];
        a0 += v0; a1 += v1; a2 += v2; a3 += v3;
        a0 += v4; a1 += v5; a2 += v6; a3 += v7;
      }
      for (; j + 4 <= nn; j += 4) {
        int s0 = __shfl(sl_cur, h32 + j + 0, 64);
        int s1 = __shfl(sl_cur, h32 + j + 1, 64);
        int s2 = __shfl(sl_cur, h32 + j + 2, 64);
        int s3 = __shfl(sl_cur, h32 + j + 3, 64);
        f32x2 v0 = *(const f32x2*)&call[(size_t)s0 * 64 + c0];
        f32x2 v1 = *(const f32x2*)&call[(size_t)s1 * 64 + c0];
        f32x2 v2 = *(const f32x2*)&call[(size_t)s2 * 64 + c0];
        f32x2 v3 = *(const f32x2*)&call[(size_t)s3 * 64 + c0];
        a0 += v0; a1 += v1; a2 += v2; a3 += v3;
      }
      for (; j < nn; j++) {
        int s = __shfl(sl_cur, h32 + j, 64);
        a0 += *(const f32x2*)&call[(size_t)s * 64 + c0];
      }
      sl_cur = sl_nx;
    }
    if (prn < nPairs)  // prefetch next pair's first srt chunk (hides under GEMM)
      slN = (begN + sub < endN) ? srt[begN + sub] : 0;
    f32x2 acc = (a0 + a1) + (a2 + a3);
    size_t idx = (size_t)r * 64 + c0;
    *(f32x2*)&nout[idx] = acc;  // cached: gather source for next shift
    float zx = bv.x, zy = bv.y;
#pragma unroll
    for (int t = 0; t < 32; ++t) {
      float nx = __shfl(acc.x, h32 + t, 64);
      float ny = __shfl(acc.y, h32 + t, 64);
      f32x2 w0 = *(const f32x2*)&Ws[(2 * t) * 64 + c0];
      f32x2 w1 = *(const f32x2*)&Ws[(2 * t + 1) * 64 + c0];
      zx = fmaf(nx, w0.x, zx);
      zy = fmaf(nx, w0.y, zy);
      zx = fmaf(ny, w1.x, zx);
      zy = fmaf(ny, w1.y, zy);
    }
    f32x2 xv = __builtin_nontemporal_load((const f32x2*)&x[idx]);
    f32x2 xo = {xv.x + zx, xv.y + zy};
    __builtin_nontemporal_store(xo, (f32x2*)&x[idx]);
    ls += xo;
    ls2.x = fmaf(xo.x, xo.x, ls2.x);
    ls2.y = fmaf(xo.y, xo.y, ls2.y);
  }
  if (stats) {
    shS[threadIdx.x] = ls;
    shS2[threadIdx.x] = ls2;
    __syncthreads();
    if (threadIdx.x < 32) {
      f32x2 s = shS[threadIdx.x], s2 = shS2[threadIdx.x];
      for (int t = threadIdx.x + 32; t < 256; t += 32) {
        s += shS[t];
        s2 += shS2[t];
      }
      atomicAdd(&stats[2 * threadIdx.x], s.x);
      atomicAdd(&stats[2 * threadIdx.x + 1], s.y);
      atomicAdd(&stats[64 + 2 * threadIdx.x], s2.x);
      atomicAdd(&stats[64 + 2 * threadIdx.x + 1], s2.y);
    }
  }
}

// ---------------- readout ----------------
__global__ void __launch_bounds__(256) k_readout(const float* __restrict__ x,
                                                 const float* __restrict__ W,
                                                 const float* __restrict__ b,
                                                 float* __restrict__ out, int nRows) {
  __shared__ float Ws[2048];
  __shared__ float bs[32];
  for (int i = threadIdx.x; i < 2048; i += 256) Ws[i] = W[i];
  if (threadIdx.x < 32) bs[threadIdx.x] = b[threadIdx.x];
  __syncthreads();
  int lane = threadIdx.x & 63;
  int ch = lane & 31;
  int w = (blockIdx.x * blockDim.x + threadIdx.x) >> 6;
  int nw = (gridDim.x * blockDim.x) >> 6;
  for (int r = w; r < nRows; r += nw) {
    float v = x[(size_t)r * 64 + lane];
    float acc = bs[ch];
#pragma unroll
    for (int i = 0; i < 64; i++) {
      float xi = __shfl(v, i, 64);
      acc = fmaf(xi, Ws[i * 32 + ch], acc);
    }
    if (lane < 32) out[(size_t)r * 32 + ch] = acc;
  }
}

extern "C" void kernel_launch(void* const* d_in, const int* in_sizes, int n_in,
                              void* d_out, int out_size, void* d_ws, size_t ws_size,
                              hipStream_t stream) {
  const float* x_bus = (const float*)d_in[0];
  const float* x_gen = (const float*)d_in[1];
  const float* riWb = (const float*)d_in[2];
  const float* ribb = (const float*)d_in[3];
  const float* riWg = (const float*)d_in[4];
  const float* ribg = (const float*)d_in[5];
  const float* bng_b = (const float*)d_in[6];
  const float* bnb_b = (const float*)d_in[7];
  const float* bng_g = (const float*)d_in[8];
  const float* bnb_g = (const float*)d_in[9];
  const float* tWb = (const float*)d_in[10];
  const float* tbb = (const float*)d_in[11];
  const float* tWg = (const float*)d_in[12];
  const float* tbg = (const float*)d_in[13];
  const float* roWb = (const float*)d_in[14];
  const float* robb = (const float*)d_in[15];
  const float* roWg = (const float*)d_in[16];
  const float* robg = (const float*)d_in[17];
  const int* ebb = (const int*)d_in[18];
  const int* gb_src = (const int*)d_in[19];
  const int* gb_dst = (const int*)d_in[20];
  const int* bg_src = (const int*)d_in[21];
  const int* bg_dst = (const int*)d_in[22];
  const int* bb_src = ebb;
  const int* bb_dst = ebb + NEBB;

  // ---- workspace layout (256B aligned segments) ----
  char* p = (char*)d_ws;
  auto take = [&](size_t bytes) -> void* {
    void* r = (void*)p;
    p += (bytes + 255) & ~(size_t)255;
    return r;
  };
  float* xb = (float*)take((size_t)NBUS * 64 * 4);
  float* xg = (float*)take((size_t)NGEN * 64 * 4);
  // combined feature buffers: bus rows [0,NBUS), gen rows [NBUS, NBUS+NGEN)
  // (NBUS*64*4 is a multiple of 256 so bus/gen sections stay contiguous)
  float* buf0 = (float*)take((size_t)(NBUS + NGEN) * 64 * 4);
  float* buf1 = (float*)take((size_t)(NBUS + NGEN) * 64 * 4);
  int* bus_off = (int*)take((size_t)(NBUS + 1) * 4);
  int* bus_cur = (int*)take((size_t)NBUS * 4);
  int* bus_srt = (int*)take((size_t)NEBUS * 4);
  int* bg_off = (int*)take((size_t)(NGEN + 1) * 4);
  int* bg_cur = (int*)take((size_t)NGEN * 4);
  int* bg_srt = (int*)take((size_t)NEBG * 4);
  int* bsums = (int*)take(256 * 4);
  float* stats0 = (float*)take(256 * 4);  // [bus s, bus s2, gen s, gen s2]
  float* stats1 = (float*)take(256 * 4);
  if ((size_t)(p - (char*)d_ws) > ws_size) return;  // ws too small -> visible validation failure

  // ---- CSR build (merged bus CSR: bb edges + gb edges with src+NBUS) ----
  hipMemsetAsync(bus_cur, 0, (size_t)NBUS * 4, stream);
  hipMemsetAsync(bg_cur, 0, (size_t)NGEN * 4, stream);
  hipMemsetAsync(stats0, 0, 512 * 4, stream);  // stats0 + stats1 (contiguous)

  k_hist<<<2048, 256, 0, stream>>>(bb_dst, bus_cur, NEBB);
  k_hist<<<256, 256, 0, stream>>>(gb_dst, bus_cur, NEGB);
  k_hist<<<256, 256, 0, stream>>>(bg_dst, bg_cur, NEBG);

  k_scan1<<<128, 256, 0, stream>>>(bus_cur, bus_off, bsums, NBUS);
  k_scan2<<<1, 256, 0, stream>>>(bsums, 128);
  k_scan3<<<512, 256, 0, stream>>>(bus_off, bus_cur, bsums, NBUS, NEBUS);

  k_scan1<<<32, 256, 0, stream>>>(bg_cur, bg_off, bsums, NGEN);
  k_scan2<<<1, 256, 0, stream>>>(bsums, 32);
  k_scan3<<<128, 256, 0, stream>>>(bg_off, bg_cur, bsums, NGEN, NEBG);

  k_fill<<<2048, 256, 0, stream>>>(bb_src, bb_dst, bus_cur, bus_srt, NEBB, 0);
  k_fill<<<256, 256, 0, stream>>>(gb_src, gb_dst, bus_cur, bus_srt, NEGB, NBUS);
  k_fill<<<256, 256, 0, stream>>>(bg_src, bg_dst, bg_cur, bg_srt, NEBG, 0);

  // ---- readin (+ layer-0 BN stats) ----
  k_readin<<<4096, 256, 0, stream>>>(x_bus, riWb, ribb, xb, NBUS, stats0);
  k_readin<<<1024, 256, 0, stream>>>(x_gen, riWg, ribg, xg, NGEN, stats0 + 128);

  // ---- residual blocks ----
  float* cur = buf0;
  float* nxt = buf1;
  for (int l = 0; l < 2; l++) {
    float* statsL = (l == 0) ? stats0 : stats1;
    k_norm_tap0<<<4096, 256, 0, stream>>>(xb, cur, statsL, 1.0f / NBUS,
                                          bng_b + l * 64, bnb_b + l * 64,
                                          tWb + (size_t)(l * 5) * 4096,
                                          tbb + (size_t)(l * 5) * 64, NBUS);
    k_norm_tap0<<<1024, 256, 0, stream>>>(xg, cur + (size_t)NBUS * 64, statsL + 128, 1.0f / NGEN,
                                          bng_g + l * 64, bnb_g + l * 64,
                                          tWg + (size_t)(l * 5) * 4096,
                                          tbg + (size_t)(l * 5) * 64, NGEN);
    for (int k = 1; k < 5; k++) {
      float* so = (l == 0 && k == 4) ? stats1 : (float*)nullptr;
      k_pull_tap<<<4096, 256, 0, stream>>>(bus_off, bus_srt, cur, xb, nxt,
                                           tWb + (size_t)(l * 5 + k) * 4096,
                                           tbb + (size_t)(l * 5 + k) * 64, NBUS, so);
      k_pull_tap<<<1024, 256, 0, stream>>>(bg_off, bg_srt, cur, xg, nxt + (size_t)NBUS * 64,
                                           tWg + (size_t)(l * 5 + k) * 4096,
                                           tbg + (size_t)(l * 5 + k) * 64, NGEN,
                                           so ? so + 128 : (float*)nullptr);
      float* t = cur; cur = nxt; nxt = t;
    }
  }

  // ---- readout ----
  k_readout<<<4096, 256, 0, stream>>>(xb, roWb, robb, (float*)d_out, NBUS);
  k_readout<<<1024, 256, 0, stream>>>(xg, roWg, robg, (float*)d_out + (size_t)NBUS * 32, NGEN);
}